// Round 5
// baseline (199.695 us; speedup 1.0000x reference)
//
#include <hip/hip_runtime.h>
#include <hip/hip_bf16.h>

typedef __bf16 bf16;
typedef __bf16 bf16x2 __attribute__((ext_vector_type(2)));
typedef __bf16 bf16x4 __attribute__((ext_vector_type(4)));
typedef __bf16 bf16x8 __attribute__((ext_vector_type(8)));
typedef float f32x4 __attribute__((ext_vector_type(4)));

// (1/16) * log2(e): softmax scale folded into exp2
#define SM_C 0.09016994374947424f

typedef __attribute__((address_space(1))) const void as1_void;
typedef __attribute__((address_space(3))) void as3_void;

// ---------------------------------------------------------------------------
// prep: Wq/Wk/Wv/Wo [k][n] f32 -> Wt[mat][n][k] bf16. LDS-tiled 32x32
// transpose: coalesced f32x4 reads, coalesced bf16x4 writes (old version did
// 64-segment gather reads). grid 256 = 4 mats x 64 tiles.
// ---------------------------------------------------------------------------
__global__ __launch_bounds__(256) void transpose_w(
    const float* __restrict__ Wq, const float* __restrict__ Wk,
    const float* __restrict__ Wv, const float* __restrict__ Wo,
    bf16* __restrict__ Wt)
{
    __shared__ float T[32][33];
    const int bid = blockIdx.x;
    const int m = bid >> 6, tile = bid & 63;
    const int tn0 = (tile >> 3) * 32, tk0 = (tile & 7) * 32;
    const float* W = (m == 0) ? Wq : (m == 1) ? Wk : (m == 2) ? Wv : Wo;

    const int t = threadIdx.x;
    const int r = t >> 3, c4 = (t & 7) * 4;

    f32x4 v = *(const f32x4*)(W + (size_t)(tk0 + r) * 256 + tn0 + c4);
#pragma unroll
    for (int j = 0; j < 4; ++j) T[r][c4 + j] = v[j];
    __syncthreads();

    bf16x4 ov;
#pragma unroll
    for (int j = 0; j < 4; ++j) ov[j] = (bf16)T[c4 + j][r];
    *(bf16x4*)(Wt + (size_t)m * 65536 + (size_t)(tn0 + r) * 256 + tk0 + c4) = ov;
}

// ---------------------------------------------------------------------------
// Fused QKV as ONE GEMM: C[32768][768] = X[32768][256] x W[256][768].
// grid (256 bm, 6 bn), 256 thr, 128x128 tile, BK=64, 37 KB LDS.
// (unchanged from round 4)
// ---------------------------------------------------------------------------
__global__ __launch_bounds__(256, 3) void qkv_gemm(
    const float* __restrict__ X, const bf16* __restrict__ Wt,
    const float* __restrict__ bq, const float* __restrict__ bk,
    const float* __restrict__ bv,
    bf16* __restrict__ Qo, bf16* __restrict__ Ko, bf16* __restrict__ Vto)
{
    __shared__ bf16 Xs[128 * 72];
    __shared__ bf16 Ws_[128 * 72];

    const int t    = threadIdx.x;
    const int lane = t & 63, wv = t >> 6;
    const int quad = lane >> 4, l16 = lane & 15;
    const int bm   = blockIdx.x;
    const int bn   = blockIdx.y;
    const int proj = bn >> 1;

    const bf16* W = Wt + (size_t)proj * 65536 + (size_t)(bn & 1) * 32768;
    const float* bias = (proj == 0) ? bq : (proj == 1) ? bk : bv;

    const int m0 = t >> 3;
    const int c0 = (t & 7) * 8;

    const f32x4 zero = {0.0f, 0.0f, 0.0f, 0.0f};
    f32x4 acc[2][8];
#pragma unroll
    for (int i = 0; i < 2; ++i)
#pragma unroll
        for (int j = 0; j < 8; ++j) acc[i][j] = zero;

    f32x4 xa[4], xb[4]; bf16x8 wp[4];
#pragma unroll
    for (int p = 0; p < 4; ++p) {
        const float* px = X + (size_t)(bm * 128 + m0 + p * 32) * 256 + c0;
        xa[p] = *(const f32x4*)px; xb[p] = *(const f32x4*)(px + 4);
        wp[p] = *(const bf16x8*)(W + (size_t)(m0 + p * 32) * 256 + c0);
    }

    for (int kt = 0; kt < 4; ++kt) {
#pragma unroll
        for (int p = 0; p < 4; ++p) {
            bf16x8 r;
#pragma unroll
            for (int j = 0; j < 4; ++j) { r[j] = (bf16)xa[p][j]; r[j + 4] = (bf16)xb[p][j]; }
            *(bf16x8*)(Xs + (m0 + p * 32) * 72 + c0) = r;
            *(bf16x8*)(Ws_ + (m0 + p * 32) * 72 + c0) = wp[p];
        }
        __syncthreads();

        if (kt < 3) {
#pragma unroll
            for (int p = 0; p < 4; ++p) {
                const float* px = X + (size_t)(bm * 128 + m0 + p * 32) * 256 + (kt + 1) * 64 + c0;
                xa[p] = *(const f32x4*)px; xb[p] = *(const f32x4*)(px + 4);
                wp[p] = *(const bf16x8*)(W + (size_t)(m0 + p * 32) * 256 + (kt + 1) * 64 + c0);
            }
        }

#pragma unroll
        for (int ks = 0; ks < 2; ++ks) {
            bf16x8 a[2], bb[8];
#pragma unroll
            for (int mt = 0; mt < 2; ++mt)
                a[mt] = *(const bf16x8*)(Xs + (wv * 32 + mt * 16 + l16) * 72 + ks * 32 + quad * 8);
#pragma unroll
            for (int nt = 0; nt < 8; ++nt)
                bb[nt] = *(const bf16x8*)(Ws_ + (nt * 16 + l16) * 72 + ks * 32 + quad * 8);
#pragma unroll
            for (int mt = 0; mt < 2; ++mt)
#pragma unroll
                for (int nt = 0; nt < 8; ++nt)
                    acc[mt][nt] = __builtin_amdgcn_mfma_f32_16x16x32_bf16(
                        a[mt], bb[nt], acc[mt][nt], 0, 0, 0);
        }
        __syncthreads();
    }

#pragma unroll
    for (int nt = 0; nt < 8; ++nt) {
        int col = (bn & 1) * 128 + nt * 16 + l16;
        float bvv = bias[col];
#pragma unroll
        for (int mt = 0; mt < 2; ++mt) {
            int grow0 = bm * 128 + wv * 32 + mt * 16 + quad * 4;
            if (proj == 2) {
                bf16x4 pk;
#pragma unroll
                for (int r = 0; r < 4; ++r) pk[r] = (bf16)(acc[mt][nt][r] + bvv);
                int b = grow0 >> 10, m = grow0 & 1023;
                *(bf16x4*)(Vto + (size_t)b * 262144 + (size_t)col * 1024 + m) = pk;
            } else {
                bf16* dst = (proj == 0) ? Qo : Ko;
#pragma unroll
                for (int r = 0; r < 4; ++r)
                    dst[(size_t)(grow0 + r) * 256 + col] = (bf16)(acc[mt][nt][r] + bvv);
            }
        }
    }
}

// ---------------------------------------------------------------------------
// Flash attention + fused O-projection, v2. 512 thr / 8 waves, grid (32 b,
// 8 qt). Waves 0-3 (group 0) process even kv tiles, waves 4-7 (group 1) odd;
// each wave owns 32 q-rows (mt=2) -> every LDS B-fragment feeds 2 MFMAs
// (halves LDS traffic per output vs the 16-row design, which was LDS-bound).
// K: unpadded [32][256] per group, staged DIRECTLY via global_load_lds with
//   pre-swizzled global source (XOR (row&7)<<4 on the 16B slot); reads use
//   the same XOR -> conflict-optimal, no register round-trip.
// QK^T computed SWAPPED (mfma(K,Q) -> lane holds kv-consecutive P values):
//   P packed as bf16x2 ds_write_b32 (8/iter vs 16 scalar b16), 1 KB/wave
//   swizzled tile reused across mt (per-wave in-order DS).
// Double-buffered K/V, ONE barrier per iteration. After the loop the two
// groups' partial O/l are merged in f32 via LDS scratch (two 128-col
// phases), then the round-4 fused O-projection runs on the merged tile.
// LDS map (bytes, total 155648):
//   loop:  G0 Ks@0[2][16384] Vs@32768[2][20480]; G1 Ks@73728 Vs@106496;
//          P@147456 (8 x 1024)
//   epi:   Os@0 [128][264]b16 (67584); scr@67584 f32[128][132] (67584);
//          lstS@135168 (512); Wos@67584 (overwrites scr after merge)
// ---------------------------------------------------------------------------
__global__ __launch_bounds__(512, 2) void flash_attn(
    const bf16* __restrict__ Qr, const bf16* __restrict__ K,
    const bf16* __restrict__ Vt, const bf16* __restrict__ Wo,
    const float* __restrict__ bo, float* __restrict__ out)
{
    __shared__ __align__(16) char smem[155648];

    const int t    = threadIdx.x;
    const int lane = t & 63, wv = t >> 6;
    const int quad = lane >> 4, l16 = lane & 15;
    const int g    = wv >> 2, wl = wv & 3;       // kv-group, wave-in-group
    const int gt   = t & 255;                    // group-local thread id
    const int b  = blockIdx.x;   // 0..31 (fastest -> XCD = b % 8)
    const int qt = blockIdx.y;   // 0..7

    char* const KsB = smem + g * 73728;            // [2][32][512B]
    char* const VsB = smem + g * 73728 + 32768;    // [2][256][80B]
    char* const Pb  = smem + 147456 + wv * 1024;   // [16][64B] swizzled
    const int psw = (l16 & 7) << 4;

    // Q fragments (used as the B operand of swapped QK^T; same reg layout)
    bf16x8 qf[2][8];
#pragma unroll
    for (int mt = 0; mt < 2; ++mt) {
        const bf16* qp = Qr + ((size_t)b * 1024 + qt * 128 + wl * 32 + mt * 16 + l16) * 256 + quad * 8;
#pragma unroll
        for (int ks = 0; ks < 8; ++ks)
            qf[mt][ks] = *(const bf16x8*)(qp + ks * 32);
    }

    const f32x4 zero = {0.0f, 0.0f, 0.0f, 0.0f};
    f32x4 o[2][16];
#pragma unroll
    for (int mt = 0; mt < 2; ++mt)
#pragma unroll
        for (int n = 0; n < 16; ++n) o[mt][n] = zero;
    float lst[2] = {0.f, 0.f};

    // V staging split: 256 thr/group, 4 x 16B each
    const int vc  = gt >> 1;          // channel 0..127 (+128 for p>=2)
    const int vk8 = (gt & 1) * 8;     // kv 0/8 (+16 for odd p)
    bf16x8 vp[4];

    // K tile T -> LDS buffer buf, direct global->LDS, source pre-swizzled
    auto gloadK = [&](int T, int buf) {
#pragma unroll
        for (int p = 0; p < 4; ++p) {
            int chunk = wl * 4 + p;                 // 16 x 1KB chunks
            int row   = chunk * 2 + (lane >> 5);
            int w16   = (lane & 31) ^ (row & 7);    // pre-swizzled 16B slot
            const bf16* gsrc = K + ((size_t)b * 1024 + T * 32 + row) * 256 + w16 * 8;
            __builtin_amdgcn_global_load_lds((as1_void*)gsrc,
                (as3_void*)(KsB + buf * 16384 + chunk * 1024), 16, 0, 0);
        }
    };
    auto vload = [&](int T) {
#pragma unroll
        for (int p = 0; p < 4; ++p) {
            int c = vc + 128 * (p >> 1), k8 = vk8 + (p & 1) * 16;
            vp[p] = *(const bf16x8*)(Vt + (size_t)b * 262144 + (size_t)c * 1024 + T * 32 + k8);
        }
    };
    auto vcommit = [&](int buf) {
#pragma unroll
        for (int p = 0; p < 4; ++p) {
            int c = vc + 128 * (p >> 1), k8 = vk8 + (p & 1) * 16;
            *(bf16x8*)(VsB + buf * 20480 + c * 80 + k8 * 2) = vp[p];
        }
    };

    // prologue: tile g -> buf0; V tile g+2 loads in flight
    gloadK(g, 0);
    vload(g); vcommit(0); vload(g + 2);

    for (int i = 0; i < 16; ++i) {
        const int buf = i & 1;
        __syncthreads();   // drains K gloads + V commits of tile for iter i

        if (i < 15) {
            gloadK(g + 2 * (i + 1), buf ^ 1);
            vcommit(buf ^ 1);              // vp holds tile g+2(i+1)
            if (i < 14) vload(g + 2 * (i + 2));
        }

        // ---- swapped S = K Q^T: C row = kv (quad*4+r), col = q (l16)
        f32x4 s[2][2];
        s[0][0] = zero; s[0][1] = zero; s[1][0] = zero; s[1][1] = zero;
        const char* Kbuf = KsB + buf * 16384;
#pragma unroll
        for (int ks = 0; ks < 8; ++ks) {
#pragma unroll
            for (int n = 0; n < 2; ++n) {
                bf16x8 kb = *(const bf16x8*)(Kbuf + (n * 16 + l16) * 512 + ((ks * 64 + quad * 16) ^ psw));
                s[0][n] = __builtin_amdgcn_mfma_f32_16x16x32_bf16(kb, qf[0][ks], s[0][n], 0, 0, 0);
                s[1][n] = __builtin_amdgcn_mfma_f32_16x16x32_bf16(kb, qf[1][ks], s[1][n], 0, 0, 0);
            }
        }

        // ---- softmax + packed P (kv-consecutive pairs) + A-frag read
        bf16x8 af[2];
#pragma unroll
        for (int mt = 0; mt < 2; ++mt) {
#pragma unroll
            for (int n = 0; n < 2; ++n) {
#pragma unroll
                for (int h = 0; h < 2; ++h) {
                    float p0 = __builtin_amdgcn_exp2f(s[mt][n][2 * h] * SM_C);
                    float p1 = __builtin_amdgcn_exp2f(s[mt][n][2 * h + 1] * SM_C);
                    lst[mt] += p0 + p1;
                    bf16x2 pk; pk[0] = (bf16)p0; pk[1] = (bf16)p1;
                    *(bf16x2*)(Pb + ((l16 * 64 + n * 32 + quad * 8 + h * 4) ^ psw)) = pk;
                }
            }
            af[mt] = *(const bf16x8*)(Pb + ((l16 * 64 + quad * 16) ^ psw));
        }

        // ---- O += P V
        const char* Vbuf = VsB + buf * 20480;
#pragma unroll
        for (int n = 0; n < 16; ++n) {
            bf16x8 vb = *(const bf16x8*)(Vbuf + (n * 16 + l16) * 80 + quad * 16);
            o[0][n] = __builtin_amdgcn_mfma_f32_16x16x32_bf16(af[0], vb, o[0][n], 0, 0, 0);
            o[1][n] = __builtin_amdgcn_mfma_f32_16x16x32_bf16(af[1], vb, o[1][n], 0, 0, 0);
        }
    }

    __syncthreads();   // end of loop: all LDS regions dead

    // ---- quad-reduce l (lane then holds full group-partial for q=mt*16+l16)
#pragma unroll
    for (int mt = 0; mt < 2; ++mt) {
        lst[mt] += __shfl_xor(lst[mt], 16, 64);
        lst[mt] += __shfl_xor(lst[mt], 32, 64);
    }

    float* const scr  = (float*)(smem + 67584);    // [col 128][132] f32
    float* const lstS = (float*)(smem + 135168);   // [128]
    bf16*  const Os   = (bf16*)smem;               // [128][264]

    // ---- group merge, phase A (cols 0..127)
    if (g == 1) {
        if (quad == 0) {
            lstS[wl * 32 + l16]      = lst[0];
            lstS[wl * 32 + 16 + l16] = lst[1];
        }
#pragma unroll
        for (int mt = 0; mt < 2; ++mt)
#pragma unroll
            for (int n = 0; n < 8; ++n)
                *(f32x4*)(scr + (size_t)(n * 16 + l16) * 132 + wl * 32 + mt * 16 + quad * 4) = o[mt][n];
    }
    __syncthreads();
    if (g == 0) {
        lst[0] += lstS[wl * 32 + l16];
        lst[1] += lstS[wl * 32 + 16 + l16];
#pragma unroll
        for (int mt = 0; mt < 2; ++mt)
#pragma unroll
            for (int n = 0; n < 8; ++n) {
                f32x4 m = *(const f32x4*)(scr + (size_t)(n * 16 + l16) * 132 + wl * 32 + mt * 16 + quad * 4);
                o[mt][n] += m;
            }
    }
    __syncthreads();
    // ---- phase B (cols 128..255)
    if (g == 1) {
#pragma unroll
        for (int mt = 0; mt < 2; ++mt)
#pragma unroll
            for (int n = 8; n < 16; ++n)
                *(f32x4*)(scr + (size_t)((n - 8) * 16 + l16) * 132 + wl * 32 + mt * 16 + quad * 4) = o[mt][n];
    }
    __syncthreads();
    if (g == 0) {
#pragma unroll
        for (int mt = 0; mt < 2; ++mt)
#pragma unroll
            for (int n = 8; n < 16; ++n) {
                f32x4 m = *(const f32x4*)(scr + (size_t)((n - 8) * 16 + l16) * 132 + wl * 32 + mt * 16 + quad * 4);
                o[mt][n] += m;
            }
        // ---- normalize, write merged attended tile (bf16, [128][264])
        float inv[2][4];
#pragma unroll
        for (int mt = 0; mt < 2; ++mt)
#pragma unroll
            for (int r = 0; r < 4; ++r)
                inv[mt][r] = 1.0f / __shfl(lst[mt], quad * 4 + r, 64);
#pragma unroll
        for (int mt = 0; mt < 2; ++mt)
#pragma unroll
            for (int n = 0; n < 16; ++n)
#pragma unroll
                for (int r = 0; r < 4; ++r)
                    Os[(size_t)(wl * 32 + mt * 16 + quad * 4 + r) * 264 + n * 16 + l16] =
                        (bf16)(o[mt][n][r] * inv[mt][r]);
    }
    __syncthreads();   // Os visible to all; scr reads done before Wos overwrite

    // ---- fused O-projection: out[128][256] = Os x Wo^T(+bo), two col-halves
    bf16* const Wos = (bf16*)(smem + 67584);
    const int rh = (wv & 1) * 64;      // wave's row strip
    const int nq = wv >> 1;            // wave's 32-col strip within half
    const size_t orow0 = (size_t)b * 1024 + qt * 128 + rh;

#pragma unroll
    for (int h = 0; h < 2; ++h) {
        if (h) __syncthreads();        // previous half's Wos reads done
#pragma unroll
        for (int i = 0; i < 8; ++i) {
            int c = t + i * 512;
            int row = c >> 5, c8 = (c & 31) * 8;
            *(bf16x8*)(Wos + row * 264 + c8) =
                *(const bf16x8*)(Wo + (size_t)(h * 128 + row) * 256 + c8);
        }
        __syncthreads();

        f32x4 acc[4][2];
#pragma unroll
        for (int mt = 0; mt < 4; ++mt) { acc[mt][0] = zero; acc[mt][1] = zero; }

#pragma unroll
        for (int ks = 0; ks < 8; ++ks) {
            bf16x8 a[4], bb[2];
#pragma unroll
            for (int mt = 0; mt < 4; ++mt)
                a[mt] = *(const bf16x8*)(Os + (size_t)(rh + mt * 16 + l16) * 264 + ks * 32 + quad * 8);
#pragma unroll
            for (int nt = 0; nt < 2; ++nt)
                bb[nt] = *(const bf16x8*)(Wos + (nq * 32 + nt * 16 + l16) * 264 + ks * 32 + quad * 8);
#pragma unroll
            for (int mt = 0; mt < 4; ++mt)
#pragma unroll
                for (int nt = 0; nt < 2; ++nt)
                    acc[mt][nt] = __builtin_amdgcn_mfma_f32_16x16x32_bf16(
                        a[mt], bb[nt], acc[mt][nt], 0, 0, 0);
        }

#pragma unroll
        for (int nt = 0; nt < 2; ++nt) {
            int col = h * 128 + nq * 32 + nt * 16 + l16;
            float bvv = bo[col];
#pragma unroll
            for (int mt = 0; mt < 4; ++mt) {
#pragma unroll
                for (int r = 0; r < 4; ++r) {
                    size_t row = orow0 + mt * 16 + quad * 4 + r;
                    out[row * 256 + col] = acc[mt][nt][r] + bvv;
                }
            }
        }
    }
}

// ---------------------------------------------------------------------------
extern "C" void kernel_launch(void* const* d_in, const int* in_sizes, int n_in,
                              void* d_out, int out_size, void* d_ws, size_t ws_size,
                              hipStream_t stream)
{
    (void)in_sizes; (void)n_in; (void)out_size; (void)ws_size;
    const float* X  = (const float*)d_in[0];
    const float* Wq = (const float*)d_in[1];
    const float* bq = (const float*)d_in[2];
    const float* Wk = (const float*)d_in[3];
    const float* bk = (const float*)d_in[4];
    const float* Wv = (const float*)d_in[5];
    const float* bv = (const float*)d_in[6];
    const float* Wo = (const float*)d_in[7];
    const float* bo = (const float*)d_in[8];
    float* out = (float*)d_out;

    const size_t NTOK = (size_t)32768 * 256;

    // workspace: Wt (4 mats = 512 KB) + Q + K + Vt
    bf16* Wt  = (bf16*)d_ws;
    bf16* Qw  = (bf16*)d_ws + 262144;
    bf16* Kw  = Qw + NTOK;
    bf16* Vtw = Kw + NTOK;

    transpose_w<<<256, 256, 0, stream>>>(Wq, Wk, Wv, Wo, Wt);
    qkv_gemm   <<<dim3(256, 6), 256, 0, stream>>>(X, Wt, bq, bk, bv, Qw, Kw, Vtw);
    flash_attn <<<dim3(32, 8),  512, 0, stream>>>(Qw, Kw, Vtw, Wt + 3 * 65536, bo, out);
}

// Round 6
// 175.513 us; speedup vs baseline: 1.1378x; 1.1378x over previous
//
#include <hip/hip_runtime.h>
#include <hip/hip_bf16.h>

typedef __bf16 bf16;
typedef __bf16 bf16x4 __attribute__((ext_vector_type(4)));
typedef __bf16 bf16x8 __attribute__((ext_vector_type(8)));
typedef float f32x4 __attribute__((ext_vector_type(4)));

// (1/16) * log2(e): softmax scale folded into exp2
#define SM_C 0.09016994374947424f

// ---------------------------------------------------------------------------
// prep: Wq/Wk/Wv/Wo [k][n] f32 -> Wt[mat][n][k] bf16. LDS-tiled 32x32
// transpose: coalesced f32x4 reads, coalesced bf16x4 writes.
// grid 256 = 4 mats x 64 tiles.
// ---------------------------------------------------------------------------
__global__ __launch_bounds__(256) void transpose_w(
    const float* __restrict__ Wq, const float* __restrict__ Wk,
    const float* __restrict__ Wv, const float* __restrict__ Wo,
    bf16* __restrict__ Wt)
{
    __shared__ float T[32][33];
    const int bid = blockIdx.x;
    const int m = bid >> 6, tile = bid & 63;
    const int tn0 = (tile >> 3) * 32, tk0 = (tile & 7) * 32;
    const float* W = (m == 0) ? Wq : (m == 1) ? Wk : (m == 2) ? Wv : Wo;

    const int t = threadIdx.x;
    const int r = t >> 3, c4 = (t & 7) * 4;

    f32x4 v = *(const f32x4*)(W + (size_t)(tk0 + r) * 256 + tn0 + c4);
#pragma unroll
    for (int j = 0; j < 4; ++j) T[r][c4 + j] = v[j];
    __syncthreads();

    bf16x4 ov;
#pragma unroll
    for (int j = 0; j < 4; ++j) ov[j] = (bf16)T[c4 + j][r];
    *(bf16x4*)(Wt + (size_t)m * 65536 + (size_t)(tn0 + r) * 256 + tk0 + c4) = ov;
}

// ---------------------------------------------------------------------------
// Fused QKV as ONE GEMM: C[32768][768] = X[32768][256] x W[256][768].
// grid (256 bm, 6 bn), 256 thr, 128x128 tile, BK=64, 36.9 KB LDS, 3 blk/CU.
// NEW this round: Q/K epilogue goes through the dead Xs/Ws LDS (C staged
// with bias into [128][132] bf16, read back 16B/lane) -> 8 dwordx4 stores
// per thread (4 x 256B dense segments/wave) instead of 64 scalar 2B stores
// (4 x 32B segments each). V path unchanged (8B packed col-major stores).
// ---------------------------------------------------------------------------
__global__ __launch_bounds__(256, 3) void qkv_gemm(
    const float* __restrict__ X, const bf16* __restrict__ Wt,
    const float* __restrict__ bq, const float* __restrict__ bk,
    const float* __restrict__ bv,
    bf16* __restrict__ Qo, bf16* __restrict__ Ko, bf16* __restrict__ Vto)
{
    __shared__ __align__(16) char qsmem[36864];
    bf16* const Xs  = (bf16*)qsmem;            // [128][72]
    bf16* const Ws_ = (bf16*)(qsmem + 18432);  // [128][72]
    bf16* const Cs  = (bf16*)qsmem;            // epilogue: [128][132]

    const int t    = threadIdx.x;
    const int lane = t & 63, wv = t >> 6;
    const int quad = lane >> 4, l16 = lane & 15;
    const int bm   = blockIdx.x;          // 0..255 (fastest -> XCD = bm%8)
    const int bn   = blockIdx.y;          // 0..5
    const int proj = bn >> 1;

    const bf16* W = Wt + (size_t)proj * 65536 + (size_t)(bn & 1) * 32768;
    const float* bias = (proj == 0) ? bq : (proj == 1) ? bk : bv;

    const int m0 = t >> 3;          // 0..31
    const int c0 = (t & 7) * 8;     // 0..56

    const f32x4 zero = {0.0f, 0.0f, 0.0f, 0.0f};
    f32x4 acc[2][8];
#pragma unroll
    for (int i = 0; i < 2; ++i)
#pragma unroll
        for (int j = 0; j < 8; ++j) acc[i][j] = zero;

    // prologue: load K-step 0
    f32x4 xa[4], xb[4]; bf16x8 wp[4];
#pragma unroll
    for (int p = 0; p < 4; ++p) {
        const float* px = X + (size_t)(bm * 128 + m0 + p * 32) * 256 + c0;
        xa[p] = *(const f32x4*)px; xb[p] = *(const f32x4*)(px + 4);
        wp[p] = *(const bf16x8*)(W + (size_t)(m0 + p * 32) * 256 + c0);
    }

    for (int kt = 0; kt < 4; ++kt) {
        // commit K-step kt to LDS
#pragma unroll
        for (int p = 0; p < 4; ++p) {
            bf16x8 r;
#pragma unroll
            for (int j = 0; j < 4; ++j) { r[j] = (bf16)xa[p][j]; r[j + 4] = (bf16)xb[p][j]; }
            *(bf16x8*)(Xs + (m0 + p * 32) * 72 + c0) = r;
            *(bf16x8*)(Ws_ + (m0 + p * 32) * 72 + c0) = wp[p];
        }
        __syncthreads();

        if (kt < 3) {   // issue next K-step loads; MFMA hides latency
#pragma unroll
            for (int p = 0; p < 4; ++p) {
                const float* px = X + (size_t)(bm * 128 + m0 + p * 32) * 256 + (kt + 1) * 64 + c0;
                xa[p] = *(const f32x4*)px; xb[p] = *(const f32x4*)(px + 4);
                wp[p] = *(const bf16x8*)(W + (size_t)(m0 + p * 32) * 256 + (kt + 1) * 64 + c0);
            }
        }

#pragma unroll
        for (int ks = 0; ks < 2; ++ks) {
            bf16x8 a[2], bb[8];
#pragma unroll
            for (int mt = 0; mt < 2; ++mt)
                a[mt] = *(const bf16x8*)(Xs + (wv * 32 + mt * 16 + l16) * 72 + ks * 32 + quad * 8);
#pragma unroll
            for (int nt = 0; nt < 8; ++nt)
                bb[nt] = *(const bf16x8*)(Ws_ + (nt * 16 + l16) * 72 + ks * 32 + quad * 8);
#pragma unroll
            for (int mt = 0; mt < 2; ++mt)
#pragma unroll
                for (int nt = 0; nt < 8; ++nt)
                    acc[mt][nt] = __builtin_amdgcn_mfma_f32_16x16x32_bf16(
                        a[mt], bb[nt], acc[mt][nt], 0, 0, 0);
        }
        __syncthreads();
    }

    // epilogue
    if (proj == 2) {
        // V: pack 4 consecutive rows -> one 8B store (col-major Vt)
#pragma unroll
        for (int nt = 0; nt < 8; ++nt) {
            int col = (bn & 1) * 128 + nt * 16 + l16;
            float bvv = bias[col];
#pragma unroll
            for (int mt = 0; mt < 2; ++mt) {
                int grow0 = bm * 128 + wv * 32 + mt * 16 + quad * 4;
                bf16x4 pk;
#pragma unroll
                for (int r = 0; r < 4; ++r) pk[r] = (bf16)(acc[mt][nt][r] + bvv);
                int b = grow0 >> 10, m = grow0 & 1023;
                *(bf16x4*)(Vto + (size_t)b * 262144 + (size_t)col * 1024 + m) = pk;
            }
        }
    } else {
        // Q/K: LDS-transit -> coalesced 16B stores
        bf16* dst = (proj == 0) ? Qo : Ko;
#pragma unroll
        for (int nt = 0; nt < 8; ++nt) {
            float bvv = bias[(bn & 1) * 128 + nt * 16 + l16];
#pragma unroll
            for (int mt = 0; mt < 2; ++mt)
#pragma unroll
                for (int r = 0; r < 4; ++r)
                    Cs[(wv * 32 + mt * 16 + quad * 4 + r) * 132 + nt * 16 + l16] =
                        (bf16)(acc[mt][nt][r] + bvv);
        }
        __syncthreads();
#pragma unroll
        for (int i = 0; i < 8; ++i) {
            int chunk = i * 256 + t;
            int row = chunk >> 4, cc = chunk & 15;
            bf16x8 v = *(const bf16x8*)(Cs + row * 132 + cc * 8);
            *(bf16x8*)(dst + (size_t)(bm * 128 + row) * 256 + (bn & 1) * 128 + cc * 8) = v;
        }
    }
}

// ---------------------------------------------------------------------------
// Flash attention + fused O-projection (round-4 version, verbatim).
// 512 thr / 8 waves, grid (32 b, 8 qt). Double-buffered K/V, one barrier
// per KV tile, P XOR-swizzle. Epilogue: normalized attended tile -> LDS
// over dead Ks/Vs; Wo staged in two 128-col halves; f32 out + bo direct.
// ---------------------------------------------------------------------------
__global__ __launch_bounds__(512, 2) void flash_attn(
    const bf16* __restrict__ Qr, const bf16* __restrict__ K,
    const bf16* __restrict__ Vt, const bf16* __restrict__ Wo,
    const float* __restrict__ bo, float* __restrict__ out)
{
    __shared__ __align__(16) char smem[142336];
    bf16* const Ksp0 = (bf16*)(smem);
    bf16* const Ksp1 = (bf16*)(smem + 16896);
    bf16* const Vsp0 = (bf16*)(smem + 33792);
    bf16* const Vsp1 = (bf16*)(smem + 54272);
    bf16* const Os   = (bf16*)(smem);
    bf16* const Wos  = (bf16*)(smem + 74752);

    const int t    = threadIdx.x;
    const int lane = t & 63, wv = t >> 6;          // wv 0..7
    const int quad = lane >> 4, l16 = lane & 15;
    const int b  = blockIdx.x;   // 0..31  (fastest -> XCD = b % 8)
    const int qt = blockIdx.y;   // 0..7

    char* const Pb = smem + 74752 + wv * 1024;     // per-wave P tile [16][32]

    // Q fragments: wave rows = qt*128 + wv*16 + l16
    bf16x8 qf[8];
    const size_t qrow = (size_t)b * 1024 + qt * 128 + wv * 16 + l16;
#pragma unroll
    for (int ks = 0; ks < 8; ++ks)
        qf[ks] = *(const bf16x8*)(Qr + qrow * 256 + ks * 32 + quad * 8);

    const f32x4 zero = {0.0f, 0.0f, 0.0f, 0.0f};
    f32x4 o[16];
#pragma unroll
    for (int n = 0; n < 16; ++n) o[n] = zero;
    float lst[4] = {0.f, 0.f, 0.f, 0.f};

    // staging index split (512 threads, 2 x 16B each for K and V)
    const int kv0 = t >> 4, kc0 = (t & 15) * 8;   // K: row kv0, elems kc0 + p*128
    const int vc0 = t >> 1, vm0 = (t & 1) * 8;    // V: row vc0, elems vm0 + p*16

    bf16x8 kp[2], vp[2];
    // prologue: tile 0 -> buf 0; tile 1 loads in flight
#pragma unroll
    for (int p = 0; p < 2; ++p) {
        kp[p] = *(const bf16x8*)(K + (size_t)(b * 1024 + kv0) * 256 + kc0 + p * 128);
        vp[p] = *(const bf16x8*)(Vt + (size_t)b * 262144 + (size_t)vc0 * 1024 + vm0 + p * 16);
    }
#pragma unroll
    for (int p = 0; p < 2; ++p) {
        *(bf16x8*)(Ksp0 + kv0 * 264 + kc0 + p * 128) = kp[p];
        *(bf16x8*)(Vsp0 + vc0 * 40 + vm0 + p * 16) = vp[p];
    }
#pragma unroll
    for (int p = 0; p < 2; ++p) {
        kp[p] = *(const bf16x8*)(K + (size_t)(b * 1024 + 32 + kv0) * 256 + kc0 + p * 128);
        vp[p] = *(const bf16x8*)(Vt + (size_t)b * 262144 + (size_t)vc0 * 1024 + 32 + vm0 + p * 16);
    }

    for (int j = 0; j < 32; ++j) {
        const bf16* Kb = (j & 1) ? Ksp1 : Ksp0;
        const bf16* Vb = (j & 1) ? Vsp1 : Vsp0;
        __syncthreads();   // tile j stores visible; prior reads of buf^1 done

        // ---- S = Q K^T
        f32x4 s[2];
        s[0] = zero; s[1] = zero;
#pragma unroll
        for (int ks = 0; ks < 8; ++ks) {
#pragma unroll
            for (int n = 0; n < 2; ++n) {
                bf16x8 bfr = *(const bf16x8*)(Kb + (n * 16 + l16) * 264 + ks * 32 + quad * 8);
                s[n] = __builtin_amdgcn_mfma_f32_16x16x32_bf16(qf[ks], bfr, s[n], 0, 0, 0);
            }
        }

        // ---- commit tile j+1 into other buffer; issue tile j+2 loads
        if (j < 31) {
            bf16* Kn = (j & 1) ? Ksp0 : Ksp1;
            bf16* Vn = (j & 1) ? Vsp0 : Vsp1;
#pragma unroll
            for (int p = 0; p < 2; ++p) {
                *(bf16x8*)(Kn + kv0 * 264 + kc0 + p * 128) = kp[p];
                *(bf16x8*)(Vn + vc0 * 40 + vm0 + p * 16) = vp[p];
            }
            if (j < 30) {
#pragma unroll
                for (int p = 0; p < 2; ++p) {
                    kp[p] = *(const bf16x8*)(K + (size_t)(b * 1024 + (j + 2) * 32 + kv0) * 256 + kc0 + p * 128);
                    vp[p] = *(const bf16x8*)(Vt + (size_t)b * 262144 + (size_t)vc0 * 1024 + (j + 2) * 32 + vm0 + p * 16);
                }
            }
        }

        // ---- no-max softmax: p = exp2(s*SM_C); P -> XOR-swizzled LDS
#pragma unroll
        for (int n = 0; n < 2; ++n) {
#pragma unroll
            for (int r = 0; r < 4; ++r) {
                float pv = __builtin_amdgcn_exp2f(s[n][r] * SM_C);
                lst[r] += pv;
                int row = quad * 4 + r;
                *(bf16*)(Pb + ((row * 64 + n * 32 + l16 * 2) ^ ((row & 7) << 4))) = (bf16)pv;
            }
        }

        // ---- O += P V
        bf16x8 af = *(const bf16x8*)(Pb + ((l16 * 64 + quad * 16) ^ ((l16 & 7) << 4)));
#pragma unroll
        for (int n = 0; n < 16; ++n) {
            bf16x8 bfr = *(const bf16x8*)(Vb + (n * 16 + l16) * 40 + quad * 8);
            o[n] = __builtin_amdgcn_mfma_f32_16x16x32_bf16(af, bfr, o[n], 0, 0, 0);
        }
    }

    __syncthreads();   // all PV reads of Ks/Vs done before Os overwrites them

    // ---- softmax denominators, normalized attended -> Os (A-frag layout)
    float inv[4];
#pragma unroll
    for (int r = 0; r < 4; ++r) {
        float l = lst[r];
#pragma unroll
        for (int off = 1; off < 16; off <<= 1)
            l += __shfl_xor(l, off, 64);
        inv[r] = 1.0f / l;
    }
#pragma unroll
    for (int n = 0; n < 16; ++n)
#pragma unroll
        for (int r = 0; r < 4; ++r)
            Os[(wv * 16 + quad * 4 + r) * 264 + n * 16 + l16] = (bf16)(o[n][r] * inv[r]);

    // ---- fused O-projection: out[128][256] = Os x Wo^T(+bo), two col-halves
    const int rh = (wv & 1) * 64;      // wave's row strip
    const int nq = wv >> 1;            // wave's 32-col strip within half
    const size_t orow0 = (size_t)b * 1024 + qt * 128 + rh;

#pragma unroll
    for (int h = 0; h < 2; ++h) {
        if (h) __syncthreads();        // previous half's Wos reads done
        // stage Wo half h: rows h*128..h*128+127 of Wo[n][k]
#pragma unroll
        for (int i = 0; i < 8; ++i) {
            int c = t + i * 512;
            int row = c >> 5, c8 = (c & 31) * 8;
            *(bf16x8*)(Wos + row * 264 + c8) =
                *(const bf16x8*)(Wo + (size_t)(h * 128 + row) * 256 + c8);
        }
        __syncthreads();               // Os (h==0) + Wos half visible

        f32x4 acc[4][2];
#pragma unroll
        for (int mt = 0; mt < 4; ++mt) { acc[mt][0] = zero; acc[mt][1] = zero; }

#pragma unroll
        for (int ks = 0; ks < 8; ++ks) {
            bf16x8 a[4], bb[2];
#pragma unroll
            for (int mt = 0; mt < 4; ++mt)
                a[mt] = *(const bf16x8*)(Os + (rh + mt * 16 + l16) * 264 + ks * 32 + quad * 8);
#pragma unroll
            for (int nt = 0; nt < 2; ++nt)
                bb[nt] = *(const bf16x8*)(Wos + (nq * 32 + nt * 16 + l16) * 264 + ks * 32 + quad * 8);
#pragma unroll
            for (int mt = 0; mt < 4; ++mt)
#pragma unroll
                for (int nt = 0; nt < 2; ++nt)
                    acc[mt][nt] = __builtin_amdgcn_mfma_f32_16x16x32_bf16(
                        a[mt], bb[nt], acc[mt][nt], 0, 0, 0);
        }

#pragma unroll
        for (int nt = 0; nt < 2; ++nt) {
            int col = h * 128 + nq * 32 + nt * 16 + l16;
            float bvv = bo[col];
#pragma unroll
            for (int mt = 0; mt < 4; ++mt) {
#pragma unroll
                for (int r = 0; r < 4; ++r) {
                    size_t row = orow0 + mt * 16 + quad * 4 + r;
                    out[row * 256 + col] = acc[mt][nt][r] + bvv;
                }
            }
        }
    }
}

// ---------------------------------------------------------------------------
extern "C" void kernel_launch(void* const* d_in, const int* in_sizes, int n_in,
                              void* d_out, int out_size, void* d_ws, size_t ws_size,
                              hipStream_t stream)
{
    (void)in_sizes; (void)n_in; (void)out_size; (void)ws_size;
    const float* X  = (const float*)d_in[0];
    const float* Wq = (const float*)d_in[1];
    const float* bq = (const float*)d_in[2];
    const float* Wk = (const float*)d_in[3];
    const float* bk = (const float*)d_in[4];
    const float* Wv = (const float*)d_in[5];
    const float* bv = (const float*)d_in[6];
    const float* Wo = (const float*)d_in[7];
    const float* bo = (const float*)d_in[8];
    float* out = (float*)d_out;

    const size_t NTOK = (size_t)32768 * 256;

    // workspace: Wt (4 mats = 512 KB) + Q + K + Vt
    bf16* Wt  = (bf16*)d_ws;
    bf16* Qw  = (bf16*)d_ws + 262144;
    bf16* Kw  = Qw + NTOK;
    bf16* Vtw = Kw + NTOK;

    transpose_w<<<256, 256, 0, stream>>>(Wq, Wk, Wv, Wo, Wt);
    qkv_gemm   <<<dim3(256, 6), 256, 0, stream>>>(X, Wt, bq, bk, bv, Qw, Kw, Vtw);
    flash_attn <<<dim3(32, 8),  512, 0, stream>>>(Qw, Kw, Vtw, Wt + 3 * 65536, bo, out);
}